// Round 7
// baseline (176.611 us; speedup 1.0000x reference)
//
#include <hip/hip_runtime.h>
#include <math.h>
#include <stdint.h>

typedef unsigned long long u64;
typedef unsigned int u32;

#define NCLS 80
#define NA   8400
#define NB   16
#define PRE_K 1000
#define NBLK 128

// ---------------- ws layout (bytes) ----------------
// f_keys : u64   [NB][NA]       @ 0         (1,075,200)
// boxes  : float4[NB][NA]       @ 1,075,200 (2,150,400)
// labels : int   [NB][NA]       @ 3,225,600 (  537,600)
// cand   : u64   [NB][1024]     @ 3,763,200 (  131,072)
// mask   : u64   [NB][1000][16] @ 3,894,272 (2,048,000)  lower-tri words only
// sem    : u32   [64]           @ 5,942,272 (zeroed via hipMemsetAsync each launch)

// Device-scope grid barrier. Safe: 128 blocks, 1 block/CU (VGPR<=128 forced
// by launch_bounds(1024)), 256 CUs -> all blocks resident at dispatch.
__device__ __forceinline__ void gbar(u32* cnt) {
    __syncthreads();
    if (threadIdx.x == 0) {
        __threadfence();                              // release published data
        u32 arrived = atomicAdd(cnt, 1u) + 1u;        // device-scope
        if (arrived < (u32)NBLK) {
            while (__hip_atomic_load(cnt, __ATOMIC_RELAXED,
                                     __HIP_MEMORY_SCOPE_AGENT) < (u32)NBLK)
                __builtin_amdgcn_s_sleep(2);
        }
        __threadfence();                              // acquire
    }
    __syncthreads();
}

// ------------------------------------------------------------------
// One persistent kernel, 4 phases (all phase bodies verbatim from the
// proven R6 kernels), 3 grid barriers. R6 post-mortem: each standalone
// kernel sat 3-5x above its floor (per-dispatch overhead + unramped
// clocks, paid 4x, plus 3 serialized launch gaps). Fusing pays it once.
// ------------------------------------------------------------------
__global__ __launch_bounds__(1024, 1) void k_fused(
    const float* __restrict__ cls0, const float* __restrict__ cls1,
    const float* __restrict__ cls2, const float* __restrict__ box0,
    const float* __restrict__ box1, const float* __restrict__ box2,
    u64* __restrict__ f_keys, float4* __restrict__ boxes,
    int* __restrict__ labels, u64* __restrict__ cand,
    u64* __restrict__ mask, u32* __restrict__ sem,
    float* __restrict__ out)
{
    __shared__ __align__(16) char shm[65536];
    int blk = blockIdx.x, tid = threadIdx.x, lane = tid & 63;

    // ================= P1: decode (grid-stride, all blocks) =================
    for (int item = blk * 1024 + tid; item < NB * NA; item += NBLK * 1024) {
        int b = item / NA, a = item - b * NA;

        const float* clsp; const float* boxp;
        int Wd, s, hw, HW;
        if (a < 6400)      { clsp = cls0; boxp = box0; Wd = 80; s = 8;  hw = a;        HW = 6400; }
        else if (a < 8000) { clsp = cls1; boxp = box1; Wd = 40; s = 16; hw = a - 6400; HW = 1600; }
        else               { clsp = cls2; boxp = box2; Wd = 20; s = 32; hw = a - 8000; HW = 400;  }

        const float* cp = clsp + (size_t)b * NCLS * HW + hw;
        float m = cp[0];
        int lab = 0;
#pragma unroll 8
        for (int c = 1; c < NCLS; ++c) {
            float v = cp[(size_t)c * HW];
            if (v > m) { m = v; lab = c; }   // strict > keeps first index on ties
        }
        double e = exp(-(double)m);
        float sc = (float)(1.0 / (1.0 + e));
        float sz = (sc > 0.25f) ? sc : 0.0f;
        f_keys[(size_t)b * NA + a] = ((u64)__float_as_uint(sz) << 32) | (u64)(~(u32)a);

        const float* bp = boxp + (size_t)b * 4 * HW + hw;
        float fs = (float)s;
        float d0 = bp[0] * fs, d1 = bp[HW] * fs, d2 = bp[2 * HW] * fs, d3 = bp[3 * HW] * fs;
        float px = (float)((hw % Wd) * s);
        float py = (float)((hw / Wd) * s);
        boxes[(size_t)b * NA + a] = make_float4(px - d0, py - d1, px + d2, py + d3);
        labels[(size_t)b * NA + a] = lab;
    }
    gbar(&sem[0]);

    // ================= P2: exact top-1000 sort (blocks 0..15) =================
    if (blk < NB) {
        u64* sh   = (u64*)shm;              // 8192 u64 = 64 KB
        u32* H    = (u32*)sh;               // 4096 bins
        u32* CS   = (u32*)(sh + 2048);      // 1024 sums
        u64* BUF  = sh + 4096;              // 2048 keys
        u32* MISC = (u32*)(sh + 6144);      // [0]=total [1]=B [2]=C [3]=cnt

        int b = blk;
        const u64* fk = f_keys + (size_t)b * NA;
        u64* cb = cand + (size_t)b * 1024;

        for (int i = tid; i < 4096; i += 1024) H[i] = 0;
        if (tid == 0) { MISC[0] = 0; MISC[1] = 0; MISC[2] = 0xFFFFFFFFu; MISC[3] = 0; }
        __syncthreads();

        for (int i = tid; i < NA; i += 1024) {
            u32 sb = (u32)(fk[i] >> 32);
            if (sb) {
                int bin = (int)(sb >> 12) - 0x3E800;
                bin = max(0, min(bin, 4095));
                atomicAdd(&H[bin], 1u);
            }
        }
        __syncthreads();

        CS[tid] = H[4*tid] + H[4*tid+1] + H[4*tid+2] + H[4*tid+3];
        __syncthreads();

        if (tid < 64) {
            u32 g = 0;
            for (int j = 0; j < 16; ++j) g += CS[lane*16 + j];
            u32 S = g;
            for (int off = 1; off < 64; off <<= 1) {
                u32 x = __shfl_down(S, off, 64);
                if (lane + off < 64) S += x;          // suffix sum over lane chunks
            }
            if (lane == 0) MISC[0] = S;
            u32 Snext = S - g;
            if (S >= PRE_K && Snext < PRE_K) {        // unique crossing lane
                u32 accAbove = Snext;
                int tB = lane * 16;
                for (int j = 15; j >= 0; --j) {
                    u32 c4 = CS[lane*16 + j];
                    if (accAbove + c4 >= PRE_K) { tB = lane*16 + j; break; }
                    accAbove += c4;
                }
                int B = 4 * tB; u32 Cv = 0;
                for (int k2 = 3; k2 >= 0; --k2) {
                    u32 hc = H[4*tB + k2];
                    if (accAbove + hc >= PRE_K) { B = 4*tB + k2; Cv = accAbove + hc; break; }
                    accAbove += hc;
                }
                MISC[1] = (u32)B; MISC[2] = Cv;
            }
        }
        __syncthreads();
        u32 total = MISC[0], Bb = MISC[1], Cv = MISC[2];
        bool fb = (total < PRE_K) || (Cv > 2048);     // block-uniform

        if (!fb) {
            for (int i = tid; i < NA; i += 1024) {
                u64 key = fk[i];
                u32 sb = (u32)(key >> 32);
                if (sb) {
                    int bin = (int)(sb >> 12) - 0x3E800;
                    bin = max(0, min(bin, 4095));
                    if ((u32)bin >= Bb) {
                        u32 p = atomicAdd(&MISC[3], 1u);
                        BUF[p] = key;
                    }
                }
            }
            __syncthreads();
            for (int i = tid; i < 2048; i += 1024) if (i >= (int)Cv) BUF[i] = 0ull;
            __syncthreads();
            for (int k = 2; k <= 2048; k <<= 1) {
                for (int j = k >> 1; j > 0; j >>= 1) {
                    int i = ((tid & ~(j-1)) << 1) | (tid & (j-1));
                    int l = i | j;
                    u64 x = BUF[i], y = BUF[l];
                    bool sw = ((i & k) == 0) ? (x < y) : (x > y);
                    if (sw) { BUF[i] = y; BUF[l] = x; }
                    __syncthreads();
                }
            }
            if (tid < PRE_K) cb[tid] = BUF[tid];
        } else {
            // -------- fallback: exact full sort --------
            __syncthreads();
            for (int i = tid; i < 8192; i += 1024) sh[i] = fk[i];
            __syncthreads();
            for (int k = 2; k <= 8192; k <<= 1) {
                for (int j = k >> 1; j > 0; j >>= 1) {
                    for (int t = tid; t < 4096; t += 1024) {
                        int i = ((t & ~(j - 1)) << 1) | (t & (j - 1));
                        int l = i | j;
                        u64 x = sh[i], y = sh[l];
                        bool sw = ((i & k) == 0) ? (x < y) : (x > y);
                        if (sw) { sh[i] = y; sh[l] = x; }
                    }
                    __syncthreads();
                }
            }
            if (tid < 256) sh[7936 + tid] = (tid < 208) ? fk[8192 + tid] : 0ull;
            __syncthreads();
            for (int k = 2; k <= 256; k <<= 1) {
                for (int j = k >> 1; j > 0; j >>= 1) {
                    for (int t = tid; t < 128; t += 1024) {
                        int i = ((t & ~(j - 1)) << 1) | (t & (j - 1));
                        int l = i | j;
                        u64 x = sh[7936 + i], y = sh[7936 + l];
                        bool sw = ((i & k) == 0) ? (x < y) : (x > y);
                        if (sw) { sh[7936 + i] = y; sh[7936 + l] = x; }
                    }
                    __syncthreads();
                }
            }
            if (tid < 1000) {
                u64 x = sh[tid];
                int lo = 0, hi = 256;
                while (lo < hi) { int mid = (lo + hi) >> 1; if (sh[7936 + mid] > x) lo = mid + 1; else hi = mid; }
                int r = tid + lo;
                if (r < PRE_K) cb[r] = x;
            }
            if (tid < 256) {
                u64 x = sh[7936 + tid];
                int lo = 0, hi = 1024;
                while (lo < hi) { int mid = (lo + hi) >> 1; if (sh[mid] > x) lo = mid + 1; else hi = mid; }
                int r = tid + lo;
                if (r < PRE_K) cb[r] = x;
            }
        }
    }
    gbar(&sem[4]);

    // ================= P3: IoU lower-tri bitmask (all 128 blocks) =================
    {
        float* sx1 = (float*)shm;           // 5 x 1000 floats = 20 KB
        float* sy1 = sx1 + 1000;
        float* sx2 = sy1 + 1000;
        float* sy2 = sx2 + 1000;
        float* sar = sy2 + 1000;

        int b = blk & 15, chunk = blk >> 4;           // 16 batches x 8 chunks
        const u64* cb = cand + (size_t)b * 1024;

        for (int i = tid; i < PRE_K; i += 1024) {
            u64 key = cb[i];
            u32 a = ~(u32)key;
            float4 bx = boxes[(size_t)b * NA + a];
            float off = (float)labels[(size_t)b * NA + a] * 8192.0f;
            float x1 = bx.x + off, y1 = bx.y + off, x2 = bx.z + off, y2 = bx.w + off;
            sx1[i] = x1; sy1[i] = y1; sx2[i] = x2; sy2[i] = y2;
            float w = fmaxf(__fsub_rn(x2, x1), 0.0f);
            float h = fmaxf(__fsub_rn(y2, y1), 0.0f);
            sar[i] = __fmul_rn(w, h);
        }
        __syncthreads();

        for (int w0 = tid; w0 < 2000; w0 += 1024) {
            int il = w0 % 125, jw = w0 / 125;
            int i = chunk * 125 + il;
            if (jw > (i >> 6)) continue;              // lower-tri words only (~46% saved)
            float ax1 = sx1[i], ay1 = sy1[i], ax2 = sx2[i], ay2 = sy2[i], aar = sar[i];
            int jmax = min(64, PRE_K - jw * 64);
            u64 bits = 0;
            for (int jj = 0; jj < jmax; ++jj) {
                int j = jw * 64 + jj;
                float lx = fmaxf(ax1, sx1[j]), ly = fmaxf(ay1, sy1[j]);
                float rx = fminf(ax2, sx2[j]), ry = fminf(ay2, sy2[j]);
                float ww = fmaxf(__fsub_rn(rx, lx), 0.0f);
                float hh = fmaxf(__fsub_rn(ry, ly), 0.0f);
                float inter = __fmul_rn(ww, hh);
                float uni = __fsub_rn(__fadd_rn(aar, sar[j]), inter);
                float den = fmaxf(uni, 1e-6f);
                float iou = inter / den;
                if (iou > 0.65f) bits |= (1ull << jj);
            }
            mask[((size_t)b * PRE_K + i) * 16 + jw] = bits;
        }
    }
    gbar(&sem[8]);

    // ================= P4: fixpoint NMS + output (blocks 0..15) =================
    if (blk < NB) {
        u64* Ksh = (u64*)shm;                        // 16 u64
        int* chg = (int*)(shm + 128);
        int b = blk, wv = tid >> 6;
        const u64* cb = cand + (size_t)b * 1024;
        const u64* mb = mask + (size_t)b * PRE_K * 16;

        bool inr = tid < PRE_K;
        u64 key = inr ? cb[tid] : 0ull;
        bool valid = inr && ((u32)(key >> 32) != 0u);   // score>0.25 iff bits nonzero

        u64 low = (1ull << (tid & 63)) - 1ull;          // lane 0 -> 0

        // row i, pre-masked to j<i; only words k<=wv were written by P3
        u64 rowm[16];
#pragma unroll
        for (int k = 0; k < 16; ++k) {
            u64 lt = (k < wv) ? ~0ull : ((k == wv) ? low : 0ull);
            u64 r = (inr && k <= wv) ? mb[(size_t)tid * 16 + k] : 0ull;
            rowm[k] = r & lt;
        }

        // K^0 = valid
        u64 v0 = __ballot(valid);
        if (lane == 0) Ksh[wv] = v0;
        __syncthreads();

        for (int it = 0; it < PRE_K; ++it) {
            u64 acc = 0;
#pragma unroll
            for (int k = 0; k < 16; ++k) acc |= rowm[k] & Ksh[k];
            bool kept = valid && (acc == 0ull);
            u64 nk = __ballot(kept);
            u64 kold = Ksh[wv];                         // uniform per wave
            __syncthreads();                            // reads of Ksh done
            if (tid == 0) *chg = 0;
            __syncthreads();
            if (lane == 0) { if (nk != kold) *chg = 1; Ksh[wv] = nk; }
            __syncthreads();
            if (*chg == 0) break;                       // fixpoint certified
        }

        // epilogue: rank kept (by index) then zero-score backfill (by index)
        u64 kf = Ksh[wv];
        int pc = 0, Kt = 0;
#pragma unroll
        for (int k = 0; k < 16; ++k) {
            u64 kk = Ksh[k];
            u64 lt = (k < wv) ? ~0ull : ((k == wv) ? low : 0ull);
            pc += __popcll(kk & lt);
            Kt += __popcll(kk);
        }
        if (inr) {
            bool kept = (kf >> (tid & 63)) & 1ull;
            int row = kept ? pc : (Kt + (tid - pc));
            if (row < 100) {
                u32 a = ~(u32)key;
                float4 bx = boxes[(size_t)b * NA + a];
                int lab = labels[(size_t)b * NA + a];
                float fsc = kept ? __uint_as_float((u32)(key >> 32)) : 0.0f;
                float* dr = out + (size_t)(b * 100 + row) * 5;
                dr[0] = bx.x; dr[1] = bx.y; dr[2] = bx.z; dr[3] = bx.w; dr[4] = fsc;
                out[(size_t)NB * 100 * 5 + b * 100 + row] = (float)lab;
            }
        }
    }
}

extern "C" void kernel_launch(void* const* d_in, const int* in_sizes, int n_in,
                              void* d_out, int out_size, void* d_ws, size_t ws_size,
                              hipStream_t stream) {
    const float* cls0 = (const float*)d_in[0];
    const float* cls1 = (const float*)d_in[1];
    const float* cls2 = (const float*)d_in[2];
    const float* box0 = (const float*)d_in[3];
    const float* box1 = (const float*)d_in[4];
    const float* box2 = (const float*)d_in[5];
    float* out = (float*)d_out;

    char* w = (char*)d_ws;
    u64*    f_keys = (u64*)(w);
    float4* boxes  = (float4*)(w + 1075200);
    int*    labels = (int*)(w + 3225600);
    u64*    cand   = (u64*)(w + 3763200);
    u64*    mask   = (u64*)(w + 3894272);
    u32*    sem    = (u32*)(w + 5942272);

    // semaphores are 0xAA-poisoned before every launch -> zero them (captured)
    hipMemsetAsync(sem, 0, 256, stream);

    k_fused<<<NBLK, 1024, 0, stream>>>(cls0, cls1, cls2, box0, box1, box2,
                                       f_keys, boxes, labels, cand, mask, sem, out);
}